// Round 15
// baseline (157.518 us; speedup 1.0000x reference)
//
#include <hip/hip_runtime.h>

#define NN 50000
#define NE 320000
#define FF 256
#define SCAN_B 196          // ceil(NN/256)
#define DEG_B  1250         // ceil(NE/256)
#define XCVT_B 12500        // NN*64/256
#define BPREP_B 128
#define NTILES 782          // ceil(NN/64)
#define MMBLK 512           // persistent k_mm blocks (2 per CU)

typedef short short8 __attribute__((ext_vector_type(8)));
typedef float f32x4 __attribute__((ext_vector_type(4)));
typedef unsigned short us4 __attribute__((ext_vector_type(4)));
typedef unsigned short us8 __attribute__((ext_vector_type(8)));

static __device__ __forceinline__ unsigned short f2bf(float f) {
    union { float f; unsigned u; } v; v.f = f;
    unsigned r = v.u + 0x7FFFu + ((v.u >> 16) & 1u);   // RNE
    return (unsigned short)(r >> 16);
}
static __device__ __forceinline__ float bf2f(unsigned short h) {
    return __uint_as_float((unsigned)h << 16);
}

// ---------------- fused pre-kernel: {deg histogram | x->bf16 swizzled | B prep} ------
// Ab row byte layout: logical byte b stored at b ^ ((row&7)<<4).
__global__ __launch_bounds__(256)
void k_pre(const int* __restrict__ ei, int* __restrict__ deg,
           const float* __restrict__ x, unsigned short* __restrict__ Ab,
           const float* __restrict__ wi, const float* __restrict__ wr,
           unsigned short* __restrict__ Bp) {
    const int b = blockIdx.x;
    if (b < DEG_B) {
        int e = b * 256 + threadIdx.x;
        if (e < NE) atomicAdd(&deg[ei[NE + e]], 1);
    } else if (b < DEG_B + XCVT_B) {
        int t = (b - DEG_B) * 256 + threadIdx.x;
        if (t < NN * 64) {
            int n = t >> 6, q = t & 63;
            float4 v = *reinterpret_cast<const float4*>(&x[(size_t)n * FF + q * 4]);
            us4 o = {f2bf(v.x), f2bf(v.y), f2bf(v.z), f2bf(v.w)};
            char* rowp = (char*)(Ab + (size_t)n * 512);
            *reinterpret_cast<us4*>(rowp + ((512 + q * 8) ^ ((n & 7) << 4))) = o;
        }
    } else {
        int t = (b - DEG_B - XCVT_B) * 256 + threadIdx.x;   // 0..32767
        int l = t & 63;
        int fb = t >> 6;          // 0..511
        int kc = fb >> 5;
        int cf = fb & 31;
        int col = cf * 16 + (l & 15);
        int kpart = col >> 8;
        int g = col & 255;
        int K0 = kc * 32 + (l >> 4) * 8;
        unsigned short* dst = Bp + (size_t)fb * 512 + (size_t)l * 8;
        #pragma unroll
        for (int e = 0; e < 8; ++e) {
            int K = K0 + e;
            const float* srcp = (K < 256) ? wi : wr;
            float v = srcp[(size_t)kpart * 65536 + (size_t)(K & 255) * 256 + g];
            dst[e] = f2bf(v);
        }
    }
}

// ---------------- scan stage 1: per-block sums ----------------
__global__ void k_scan1(const int* __restrict__ deg, int* __restrict__ bsum) {
    __shared__ int s[256];
    int i = blockIdx.x * 256 + threadIdx.x;
    s[threadIdx.x] = (i < NN) ? deg[i] : 0;
    __syncthreads();
    for (int d = 128; d > 0; d >>= 1) {
        if (threadIdx.x < d) s[threadIdx.x] += s[threadIdx.x + d];
        __syncthreads();
    }
    if (threadIdx.x == 0) bsum[blockIdx.x] = s[0];
}

// ---------------- scan stage 2: local scan with inline block-offset scan -------------
__global__ void k_scan3(const int* __restrict__ deg, const int* __restrict__ bsum,
                        int* __restrict__ off, int* __restrict__ cur,
                        float* __restrict__ dinv) {
    __shared__ int sb[256];
    __shared__ int s[256];
    const int t = threadIdx.x;
    int bv = (t < SCAN_B) ? bsum[t] : 0;
    sb[t] = bv;
    __syncthreads();
    for (int d = 1; d < 256; d <<= 1) {
        int u = (t >= d) ? sb[t - d] : 0;
        __syncthreads();
        sb[t] += u;
        __syncthreads();
    }
    const int boff = sb[blockIdx.x] - bsum[blockIdx.x];
    int i = blockIdx.x * 256 + t;
    int v = (i < NN) ? deg[i] : 0;
    s[t] = v;
    __syncthreads();
    for (int d = 1; d < 256; d <<= 1) {
        int u = (t >= d) ? s[t - d] : 0;
        __syncthreads();
        s[t] += u;
        __syncthreads();
    }
    if (i < NN) {
        int excl = boff + s[t] - v;
        off[i] = excl;
        cur[i] = excl;
        dinv[i] = v > 0 ? rsqrtf((float)v) : 0.f;
    }
}

// ---------------- CSR fill ----------------
__global__ void k_fill(const int* __restrict__ ei, int* __restrict__ cur,
                       int* __restrict__ csr_src) {
    int e = blockIdx.x * blockDim.x + threadIdx.x;
    if (e < NE) {
        int dst = ei[NE + e];
        int pos = atomicAdd(&cur[dst], 1);
        csr_src[pos] = ei[e];
    }
}

// ---------------- aggregation v2: TWO nodes per wave (32 lanes x 16B each) ----------
__global__ __launch_bounds__(256)
void k_agg(const int* __restrict__ off, const int* __restrict__ deg,
           const int* __restrict__ csr_src, const float* __restrict__ dinv,
           unsigned short* __restrict__ Ab) {
    int wid = (blockIdx.x * blockDim.x + threadIdx.x) >> 6;
    if (wid >= NN / 2) return;
    int l = threadIdx.x & 63;
    int n = wid * 2 + (l >> 5);          // half-wave 0 -> even node, half-wave 1 -> odd
    int start = off[n];
    int d = deg[n];
    float di = dinv[n];
    const char* base = (const char*)Ab;
    const int lq = (l & 31) * 16;        // this lane's 16B slice of the 512B row
    const int lb = 512 + lq;             // logical byte in x-half
    float acc[8];
    #pragma unroll
    for (int j = 0; j < 8; ++j) acc[j] = 0.f;
    int e = 0;
    for (; e + 4 <= d; e += 4) {
        int s0 = csr_src[start + e + 0];
        int s1 = csr_src[start + e + 1];
        int s2 = csr_src[start + e + 2];
        int s3 = csr_src[start + e + 3];
        us8 v0 = *reinterpret_cast<const us8*>(base + (size_t)s0 * 1024 + (lb ^ ((s0 & 7) << 4)));
        us8 v1 = *reinterpret_cast<const us8*>(base + (size_t)s1 * 1024 + (lb ^ ((s1 & 7) << 4)));
        us8 v2 = *reinterpret_cast<const us8*>(base + (size_t)s2 * 1024 + (lb ^ ((s2 & 7) << 4)));
        us8 v3 = *reinterpret_cast<const us8*>(base + (size_t)s3 * 1024 + (lb ^ ((s3 & 7) << 4)));
        float w0 = di * dinv[s0], w1 = di * dinv[s1], w2 = di * dinv[s2], w3 = di * dinv[s3];
        #pragma unroll
        for (int j = 0; j < 8; ++j)
            acc[j] = fmaf(w0, bf2f(v0[j]), fmaf(w1, bf2f(v1[j]),
                     fmaf(w2, bf2f(v2[j]), fmaf(w3, bf2f(v3[j]), acc[j]))));
    }
    for (; e < d; ++e) {
        int s0 = csr_src[start + e];
        us8 v0 = *reinterpret_cast<const us8*>(base + (size_t)s0 * 1024 + (lb ^ ((s0 & 7) << 4)));
        float w0 = di * dinv[s0];
        #pragma unroll
        for (int j = 0; j < 8; ++j)
            acc[j] = fmaf(w0, bf2f(v0[j]), acc[j]);
    }
    us8 o;
    #pragma unroll
    for (int j = 0; j < 8; ++j) o[j] = f2bf(acc[j]);
    *reinterpret_cast<us8*>((char*)Ab + (size_t)n * 1024 + (lq ^ ((n & 7) << 4))) = o;
}

// ---------------- MFMA GEMM + epilogue: persistent blocks (tail-balanced) ----------
#define LOADB(dst, kc_)                                                           \
    {                                                                             \
        dst[0] = *reinterpret_cast<const short8*>(bpb + (kc_) * 32768 + (2 * w + 0) * 1024);        \
        dst[1] = *reinterpret_cast<const short8*>(bpb + (kc_) * 32768 + (2 * w + 1) * 1024);        \
        dst[2] = *reinterpret_cast<const short8*>(bpb + (kc_) * 32768 + (16 + 2 * w) * 1024);       \
        dst[3] = *reinterpret_cast<const short8*>(bpb + (kc_) * 32768 + (17 + 2 * w) * 1024);       \
    }
#define LOADA1K(dst, ab, kc2_)                                                    \
    {                                                                             \
        _Pragma("unroll")                                                         \
        for (int rf = 0; rf < 4; ++rf)                                            \
            dst[rf] = *reinterpret_cast<const short8*>((ab) + rf * 16384 + (kc2_) * 128); \
    }
#define MFMA4(aset, bset)                                                         \
    {                                                                             \
        _Pragma("unroll")                                                         \
        for (int rf = 0; rf < 4; ++rf)                                            \
            _Pragma("unroll")                                                     \
            for (int c = 0; c < 4; ++c)                                           \
                acc[rf][c] = __builtin_amdgcn_mfma_f32_16x16x32_bf16(aset[rf], bset[c], acc[rf][c], 0, 0, 0); \
    }

__global__ __launch_bounds__(512, 4)
void k_mm(const unsigned short* __restrict__ Ab, const unsigned short* __restrict__ Bp,
          const float* __restrict__ bias, float* __restrict__ out) {
    __shared__ char smem[65536];   // A panel, swizzled rows (1 KB each)

    const int l = threadIdx.x & 63;
    const int w = threadIdx.x >> 6;
    const int p = l & 7, q = l >> 4;
    const int aoff = (l & 15) * 1024 + ((p >> 2) << 6) + ((q ^ (p & 3)) << 4);
    const char* abase0 = smem + aoff;
    const char* abase1 = smem + (aoff ^ 64);
    const char* bpb = (const char*)(Bp + (size_t)l * 8);

    for (int tile = blockIdx.x; tile < NTILES; tile += MMBLK) {
        const int row0 = tile * 64;

        // ---- stage: wave w copies rows {j*8 + w}, one 1KB row per global_load_lds
        {
            const char* base = (const char*)Ab;
            #pragma unroll
            for (int j = 0; j < 8; ++j) {
                int rl = j * 8 + w;
                int rsrc = row0 + rl; if (rsrc >= NN) rsrc = NN - 1;   // clamp tail
                const char* gp = base + (size_t)rsrc * 1024 + l * 16;
                __builtin_amdgcn_global_load_lds(
                    (const __attribute__((address_space(1))) void*)gp,
                    (__attribute__((address_space(3))) void*)(smem + rl * 1024),
                    16, 0, 0);
            }
        }
        __syncthreads();

        f32x4 acc[4][4];
        #pragma unroll
        for (int i = 0; i < 4; ++i)
            #pragma unroll
            for (int j = 0; j < 4; ++j) acc[i][j] = (f32x4){0.f, 0.f, 0.f, 0.f};

        short8 b0[4], b1[4], a[4];
        LOADB(b0, 0)
        #pragma unroll 1
        for (int kc2 = 0; kc2 < 7; ++kc2) {
            LOADA1K(a, abase0, kc2)
            LOADB(b1, 2 * kc2 + 1)
            MFMA4(a, b0)
            LOADA1K(a, abase1, kc2)
            LOADB(b0, 2 * kc2 + 2)
            MFMA4(a, b1)
        }
        {
            LOADA1K(a, abase0, 7)
            LOADB(b1, 15)
            MFMA4(a, b0)
            LOADA1K(a, abase1, 7)
            MFMA4(a, b1)
        }

        __syncthreads();   // Ab aliases out: all waves' A reads must finish before stores

        #pragma unroll
        for (int rf = 0; rf < 4; ++rf) {
            const int rl0 = rf * 16 + (l >> 4) * 4;
            #pragma unroll
            for (int j = 0; j < 4; ++j) {
                int rl = rl0 + j;
                int r = row0 + rl;
                if (r >= NN) continue;
                int sw = (rl & 7) << 4;
                #pragma unroll
                for (int c = 0; c < 2; ++c) {
                    int gg = w * 32 + c * 16 + (l & 15);
                    unsigned short xb =
                        *reinterpret_cast<const unsigned short*>(&smem[rl * 1024 + ((512 + gg * 2) ^ sw)]);
                    float xv = bf2f(xb);
                    float c0 = acc[rf][c][j] + bias[gg];
                    float c1 = acc[rf][c + 2][j] + bias[256 + gg];
                    float arma = 0.5f * (fmaxf(c0, 0.f) + fmaxf(c1, 0.f));
                    out[(size_t)r * FF + gg] = xv + fmaxf(arma, 0.f);
                }
            }
        }
        __syncthreads();   // epilogue LDS reads done before next tile's staging
    }
}

extern "C" void kernel_launch(void* const* d_in, const int* in_sizes, int n_in,
                              void* d_out, int out_size, void* d_ws, size_t ws_size,
                              hipStream_t stream) {
    const float* x    = (const float*)d_in[0];
    const int*   ei   = (const int*)d_in[1];
    const float* wi   = (const float*)d_in[2];
    const float* wr   = (const float*)d_in[3];
    const float* bias = (const float*)d_in[4];
    float* out = (float*)d_out;

    // workspace (~2.6 MB)
    int*   deg     = (int*)d_ws;              // NN
    int*   off     = deg + NN;                // NN
    int*   cur     = off + NN;                // NN
    int*   csr_src = cur + NN;                // NE
    float* dinv    = (float*)(csr_src + NE);  // NN
    int*   bsum    = (int*)(dinv + NN);       // SCAN_B
    unsigned short* Bp = (unsigned short*)(bsum + SCAN_B);   // 512*512 bf16 = 512 KB
    unsigned short* Ab = (unsigned short*)d_out;             // 50000 x 512 bf16 == d_out bytes

    hipMemsetAsync(deg, 0, NN * sizeof(int), stream);

    k_pre  <<<DEG_B + XCVT_B + BPREP_B, 256, 0, stream>>>(ei, deg, x, Ab, wi, wr, Bp);
    k_scan1<<<SCAN_B, 256, 0, stream>>>(deg, bsum);
    k_scan3<<<SCAN_B, 256, 0, stream>>>(deg, bsum, off, cur, dinv);
    k_fill <<<(NE + 255) / 256, 256, 0, stream>>>(ei, cur, csr_src);
    k_agg  <<<(NN / 2 * 64 + 255) / 256, 256, 0, stream>>>(off, deg, csr_src, dinv, Ab);
    k_mm   <<<MMBLK, 512, 0, stream>>>(Ab, Bp, bias, out);
}

// Round 16
// 108.226 us; speedup vs baseline: 1.4555x; 1.4555x over previous
//
#include <hip/hip_runtime.h>

#define NN 50000
#define NE 320000
#define FF 256
#define FILL_B 1250         // ceil(NE/256)
#define XCVT_B 12500        // NN*64/256
#define BPREP_B 128
#define PSTR 64             // padded adjacency stride (max supported in-degree)

typedef short short8 __attribute__((ext_vector_type(8)));
typedef float f32x4 __attribute__((ext_vector_type(4)));
typedef unsigned short us4 __attribute__((ext_vector_type(4)));
typedef unsigned short us8 __attribute__((ext_vector_type(8)));

static __device__ __forceinline__ unsigned short f2bf(float f) {
    union { float f; unsigned u; } v; v.f = f;
    unsigned r = v.u + 0x7FFFu + ((v.u >> 16) & 1u);   // RNE
    return (unsigned short)(r >> 16);
}
static __device__ __forceinline__ float bf2f(unsigned short h) {
    return __uint_as_float((unsigned)h << 16);
}

// ---- fused pre-kernel: {padded-CSR fill | x->bf16 swizzled | B prep} ----------------
// Ab row byte layout: logical byte b stored at b ^ ((row&7)<<4).
// Padded adjacency: padded[dst*PSTR + slot] = src, cnt[dst] = in-degree.
__global__ __launch_bounds__(256)
void k_pre(const int* __restrict__ ei, int* __restrict__ cnt, int* __restrict__ padded,
           const float* __restrict__ x, unsigned short* __restrict__ Ab,
           const float* __restrict__ wi, const float* __restrict__ wr,
           unsigned short* __restrict__ Bp) {
    const int b = blockIdx.x;
    if (b < FILL_B) {
        int e = b * 256 + threadIdx.x;
        if (e < NE) {
            int src = ei[e];
            int dst = ei[NE + e];
            int slot = atomicAdd(&cnt[dst], 1);
            if (slot < PSTR) padded[(size_t)dst * PSTR + slot] = src;
        }
    } else if (b < FILL_B + XCVT_B) {
        int t = (b - FILL_B) * 256 + threadIdx.x;
        if (t < NN * 64) {
            int n = t >> 6, q = t & 63;
            float4 v = *reinterpret_cast<const float4*>(&x[(size_t)n * FF + q * 4]);
            us4 o = {f2bf(v.x), f2bf(v.y), f2bf(v.z), f2bf(v.w)};
            char* rowp = (char*)(Ab + (size_t)n * 512);
            *reinterpret_cast<us4*>(rowp + ((512 + q * 8) ^ ((n & 7) << 4))) = o;
        }
    } else {
        int t = (b - FILL_B - XCVT_B) * 256 + threadIdx.x;   // 0..32767
        int l = t & 63;
        int fb = t >> 6;          // 0..511
        int kc = fb >> 5;
        int cf = fb & 31;
        int col = cf * 16 + (l & 15);
        int kpart = col >> 8;
        int g = col & 255;
        int K0 = kc * 32 + (l >> 4) * 8;
        unsigned short* dst = Bp + (size_t)fb * 512 + (size_t)l * 8;
        #pragma unroll
        for (int e = 0; e < 8; ++e) {
            int K = K0 + e;
            const float* srcp = (K < 256) ? wi : wr;
            float v = srcp[(size_t)kpart * 65536 + (size_t)(K & 255) * 256 + g];
            dst[e] = f2bf(v);
        }
    }
}

// ---- aggregation: 2 nodes/wave, padded adjacency, inline guarded rsqrt --------------
// Reads Ab x-half (bf16, swizzled), writes Ab y-half.
__global__ __launch_bounds__(256)
void k_agg(const int* __restrict__ cnt, const int* __restrict__ padded,
           unsigned short* __restrict__ Ab) {
    int wid = (blockIdx.x * blockDim.x + threadIdx.x) >> 6;
    if (wid >= NN / 2) return;
    int l = threadIdx.x & 63;
    int n = wid * 2 + (l >> 5);          // half-wave 0 -> even node, half-wave 1 -> odd
    int d = cnt[n];
    float di = d > 0 ? rsqrtf((float)d) : 0.f;
    if (d > PSTR) d = PSTR;
    const int* pp = padded + (size_t)n * PSTR;
    const char* base = (const char*)Ab;
    const int lq = (l & 31) * 16;        // this lane's 16B slice of the 512B row
    const int lb = 512 + lq;             // logical byte in x-half
    float acc[8];
    #pragma unroll
    for (int j = 0; j < 8; ++j) acc[j] = 0.f;
    int e = 0;
    for (; e + 4 <= d; e += 4) {
        int s0 = pp[e + 0];
        int s1 = pp[e + 1];
        int s2 = pp[e + 2];
        int s3 = pp[e + 3];
        us8 v0 = *reinterpret_cast<const us8*>(base + (size_t)s0 * 1024 + (lb ^ ((s0 & 7) << 4)));
        us8 v1 = *reinterpret_cast<const us8*>(base + (size_t)s1 * 1024 + (lb ^ ((s1 & 7) << 4)));
        us8 v2 = *reinterpret_cast<const us8*>(base + (size_t)s2 * 1024 + (lb ^ ((s2 & 7) << 4)));
        us8 v3 = *reinterpret_cast<const us8*>(base + (size_t)s3 * 1024 + (lb ^ ((s3 & 7) << 4)));
        int c0 = cnt[s0], c1 = cnt[s1], c2 = cnt[s2], c3 = cnt[s3];
        float w0 = di * (c0 > 0 ? rsqrtf((float)c0) : 0.f);
        float w1 = di * (c1 > 0 ? rsqrtf((float)c1) : 0.f);
        float w2 = di * (c2 > 0 ? rsqrtf((float)c2) : 0.f);
        float w3 = di * (c3 > 0 ? rsqrtf((float)c3) : 0.f);
        #pragma unroll
        for (int j = 0; j < 8; ++j)
            acc[j] = fmaf(w0, bf2f(v0[j]), fmaf(w1, bf2f(v1[j]),
                     fmaf(w2, bf2f(v2[j]), fmaf(w3, bf2f(v3[j]), acc[j]))));
    }
    for (; e < d; ++e) {
        int s0 = pp[e];
        us8 v0 = *reinterpret_cast<const us8*>(base + (size_t)s0 * 1024 + (lb ^ ((s0 & 7) << 4)));
        int c0 = cnt[s0];
        float w0 = di * (c0 > 0 ? rsqrtf((float)c0) : 0.f);
        #pragma unroll
        for (int j = 0; j < 8; ++j)
            acc[j] = fmaf(w0, bf2f(v0[j]), acc[j]);
    }
    us8 o;
    #pragma unroll
    for (int j = 0; j < 8; ++j) o[j] = f2bf(acc[j]);
    *reinterpret_cast<us8*>((char*)Ab + (size_t)n * 1024 + (lq ^ ((n & 7) << 4))) = o;
}

// ---- MFMA GEMM + epilogue (R14 proven: 782 blocks, LDS A panel, B reg ping-pong) ----
#define LOADB(dst, kc_)                                                           \
    {                                                                             \
        dst[0] = *reinterpret_cast<const short8*>(bpb + (kc_) * 32768 + (2 * w + 0) * 1024);        \
        dst[1] = *reinterpret_cast<const short8*>(bpb + (kc_) * 32768 + (2 * w + 1) * 1024);        \
        dst[2] = *reinterpret_cast<const short8*>(bpb + (kc_) * 32768 + (16 + 2 * w) * 1024);       \
        dst[3] = *reinterpret_cast<const short8*>(bpb + (kc_) * 32768 + (17 + 2 * w) * 1024);       \
    }
#define LOADA1K(dst, ab, kc2_)                                                    \
    {                                                                             \
        _Pragma("unroll")                                                         \
        for (int rf = 0; rf < 4; ++rf)                                            \
            dst[rf] = *reinterpret_cast<const short8*>((ab) + rf * 16384 + (kc2_) * 128); \
    }
#define MFMA4(aset, bset)                                                         \
    {                                                                             \
        _Pragma("unroll")                                                         \
        for (int rf = 0; rf < 4; ++rf)                                            \
            _Pragma("unroll")                                                     \
            for (int c = 0; c < 4; ++c)                                           \
                acc[rf][c] = __builtin_amdgcn_mfma_f32_16x16x32_bf16(aset[rf], bset[c], acc[rf][c], 0, 0, 0); \
    }

__global__ __launch_bounds__(512, 4)
void k_mm(const unsigned short* __restrict__ Ab, const unsigned short* __restrict__ Bp,
          const float* __restrict__ bias, float* __restrict__ out) {
    __shared__ char smem[65536];   // A panel, swizzled rows (1 KB each)

    const int l = threadIdx.x & 63;
    const int w = threadIdx.x >> 6;
    const int row0 = blockIdx.x * 64;

    {
        const char* base = (const char*)Ab;
        #pragma unroll
        for (int j = 0; j < 8; ++j) {
            int rl = j * 8 + w;
            int rsrc = row0 + rl; if (rsrc >= NN) rsrc = NN - 1;   // clamp tail (masked later)
            const char* gp = base + (size_t)rsrc * 1024 + l * 16;
            __builtin_amdgcn_global_load_lds(
                (const __attribute__((address_space(1))) void*)gp,
                (__attribute__((address_space(3))) void*)(smem + rl * 1024),
                16, 0, 0);
        }
    }
    __syncthreads();

    f32x4 acc[4][4];
    #pragma unroll
    for (int i = 0; i < 4; ++i)
        #pragma unroll
        for (int j = 0; j < 4; ++j) acc[i][j] = (f32x4){0.f, 0.f, 0.f, 0.f};

    const int p = l & 7, q = l >> 4;
    const char* abase0 = smem + (l & 15) * 1024 + ((p >> 2) << 6) + ((q ^ (p & 3)) << 4);
    const char* abase1 = smem + (((size_t)(abase0 - smem)) ^ 64);
    const char* bpb = (const char*)(Bp + (size_t)l * 8);

    short8 b0[4], b1[4], a[4];
    LOADB(b0, 0)
    #pragma unroll 1
    for (int kc2 = 0; kc2 < 7; ++kc2) {
        LOADA1K(a, abase0, kc2)
        LOADB(b1, 2 * kc2 + 1)
        MFMA4(a, b0)
        LOADA1K(a, abase1, kc2)
        LOADB(b0, 2 * kc2 + 2)
        MFMA4(a, b1)
    }
    {
        LOADA1K(a, abase0, 7)
        LOADB(b1, 15)
        MFMA4(a, b0)
        LOADA1K(a, abase1, 7)
        MFMA4(a, b1)
    }

    __syncthreads();   // Ab aliases out: all waves' A reads must finish before stores

    #pragma unroll
    for (int rf = 0; rf < 4; ++rf) {
        const int rl0 = rf * 16 + (l >> 4) * 4;
        #pragma unroll
        for (int j = 0; j < 4; ++j) {
            int rl = rl0 + j;
            int r = row0 + rl;
            if (r >= NN) continue;
            int sw = (rl & 7) << 4;
            #pragma unroll
            for (int c = 0; c < 2; ++c) {
                int gg = w * 32 + c * 16 + (l & 15);
                unsigned short xb =
                    *reinterpret_cast<const unsigned short*>(&smem[rl * 1024 + ((512 + gg * 2) ^ sw)]);
                float xv = bf2f(xb);
                float c0 = acc[rf][c][j] + bias[gg];
                float c1 = acc[rf][c + 2][j] + bias[256 + gg];
                float arma = 0.5f * (fmaxf(c0, 0.f) + fmaxf(c1, 0.f));
                out[(size_t)r * FF + gg] = xv + fmaxf(arma, 0.f);
            }
        }
    }
}

extern "C" void kernel_launch(void* const* d_in, const int* in_sizes, int n_in,
                              void* d_out, int out_size, void* d_ws, size_t ws_size,
                              hipStream_t stream) {
    const float* x    = (const float*)d_in[0];
    const int*   ei   = (const int*)d_in[1];
    const float* wi   = (const float*)d_in[2];
    const float* wr   = (const float*)d_in[3];
    const float* bias = (const float*)d_in[4];
    float* out = (float*)d_out;

    // workspace (~13.5 MB)
    int* cnt    = (int*)d_ws;                 // NN
    int* padded = cnt + NN;                   // NN * PSTR
    unsigned short* Bp = (unsigned short*)(padded + (size_t)NN * PSTR);  // 512*512 bf16
    unsigned short* Ab = (unsigned short*)d_out;                         // NN x 512 bf16

    hipMemsetAsync(cnt, 0, NN * sizeof(int), stream);

    k_pre<<<FILL_B + XCVT_B + BPREP_B, 256, 0, stream>>>(ei, cnt, padded, x, Ab, wi, wr, Bp);
    k_agg<<<(NN / 2 * 64 + 255) / 256, 256, 0, stream>>>(cnt, padded, Ab);
    k_mm <<<(NN + 63) / 64, 512, 0, stream>>>(Ab, Bp, bias, out);
}